// Round 10
// baseline (98.502 us; speedup 1.0000x reference)
//
#include <hip/hip_runtime.h>

#define IN_F 4096
#define OUT_F 11008
#define M_ROWS 64
#define KSPLIT 16
#define GPB 2                       // k-groups per block (32/KSPLIT)
#define NT_BLK 128                  // n-cols per block: 4 waves x 2 strips x 16
#define NBLK_N (OUT_F / NT_BLK)     // 86 -> grid 1376 = 5.4 blocks/CU
#define QZ_WORDS (OUT_F / 8)        // 1376
#define SLICE (M_ROWS * OUT_F)      // 704512 elements per k-split partial

typedef __attribute__((ext_vector_type(8))) short short8;
typedef __attribute__((ext_vector_type(8))) _Float16 half8;
typedef __attribute__((ext_vector_type(4))) float float4v;

// RNE fp32 -> bf16 (proven R1/R3-R8)
__device__ __forceinline__ short f2bf(float f) {
    unsigned u = __builtin_bit_cast(unsigned, f);
    return (short)((u + 0x7FFFu + ((u >> 16) & 1u)) >> 16);
}
// truncating fp32 -> bf16 (B-side, proven R3-R8)
__device__ __forceinline__ short f2bf_t(float f) {
    return (short)(__builtin_bit_cast(unsigned, f) >> 16);
}

// ---- pass 1: x [64,4096] fp32 -> xbf2 [512][64][8] bf16 (k-octet-major) ----
__global__ __launch_bounds__(256) void cvt_kernel(const float* __restrict__ x,
                                                  short* __restrict__ xbf2) {
    const int T = blockIdx.x * 256 + threadIdx.x;
    const int u = T >> 6, m = T & 63;
    const float* src = x + m * IN_F + u * 8;
    float4v f0 = *(const float4v*)src;
    float4v f1 = *(const float4v*)(src + 4);
    short8 h;
#pragma unroll
    for (int j = 0; j < 4; ++j) {
        h[j]     = f2bf(f0[j]);
        h[j + 4] = f2bf(f1[j]);
    }
    *(short8*)(xbf2 + T * 8) = h;
}

// ---- pass 2: fused dequant + bf16 MFMA. No LDS/barriers; hoisted loads ----
__global__ __launch_bounds__(256, 3) void qlin_kernel(
    const short* __restrict__ xbf2,     // [512][64][8] bf16
    const int*   __restrict__ qweight,  // [512, 11008]
    const int*   __restrict__ qzeros,   // [32, 1376]
    const float* __restrict__ scales,   // [32, 11008]
    _Float16* __restrict__ part)        // [KSPLIT][64][11008] fp16 partials
{
    const int blk  = blockIdx.x;
    const int nb   = blk % NBLK_N;
    const int kg   = blk / NBLK_N;
    const int t    = threadIdx.x;
    const int wave = t >> 6;
    const int lane = t & 63;
    const int q    = lane >> 4;
    const int nl   = lane & 15;
    const int n0   = nb * NT_BLK + wave * 32 + nl;
    const int n1   = n0 + 16;
    const int shz  = (n0 & 7) * 4;      // same for n1
    const int g0   = kg * GPB;

    // ---------------- phase 1: issue every global load up front ----------------
    int   qw[GPB * 8];        // [gi][strip*4 + kk]
    int   zr0[GPB], zr1[GPB];
    float s0a[GPB], s1a[GPB];
#pragma unroll
    for (int gi = 0; gi < GPB; ++gi) {
        const int g = g0 + gi;
#pragma unroll
        for (int kk = 0; kk < 4; ++kk) {
            const int row = g * 16 + kk * 4 + q;
            qw[gi * 8 + kk]     = qweight[row * OUT_F + n0];
            qw[gi * 8 + kk + 4] = qweight[row * OUT_F + n1];
        }
        zr0[gi] = qzeros[g * QZ_WORDS + (n0 >> 3)];
        zr1[gi] = qzeros[g * QZ_WORDS + (n1 >> 3)];
        s0a[gi] = scales[g * OUT_F + n0];
        s1a[gi] = scales[g * OUT_F + n1];
    }

    float4v acc0[4], acc1[4];
#pragma unroll
    for (int i = 0; i < 4; ++i) {
        acc0[i] = (float4v){0.f, 0.f, 0.f, 0.f};
        acc1[i] = (float4v){0.f, 0.f, 0.f, 0.f};
    }

    const short* abase_nl = xbf2 + nl * 8;

    // ---------------- phase 2: dequant + MFMA ----------------
#pragma unroll
    for (int gi = 0; gi < GPB; ++gi) {
        const int g = g0 + gi;
        const float s0  = s0a[gi];
        const float s1  = s1a[gi];
        const float nz0 = -s0 * (float)(((zr0[gi] >> shz) & 15) + 1);
        const float nz1 = -s1 * (float)(((zr1[gi] >> shz) & 15) + 1);

#pragma unroll
        for (int kk = 0; kk < 4; ++kk) {
            const int w0 = qw[gi * 8 + kk];
            const int w1 = qw[gi * 8 + kk + 4];
            short8 b0, b1;
#pragma unroll
            for (int j = 0; j < 8; ++j) {
                b0[j] = f2bf_t(fmaf(s0, (float)((w0 >> (4 * j)) & 15), nz0));
                b1[j] = f2bf_t(fmaf(s1, (float)((w1 >> (4 * j)) & 15), nz1));
            }
            const int u = kk * 4 + q;
            const short* abase = abase_nl + (g * 16 + u) * 64 * 8;
#pragma unroll
            for (int mt = 0; mt < 4; ++mt) {
                short8 a = *(const short8*)(abase + mt * 16 * 8);
                acc0[mt] = __builtin_amdgcn_mfma_f32_16x16x32_bf16(a, b0, acc0[mt], 0, 0, 0);
                acc1[mt] = __builtin_amdgcn_mfma_f32_16x16x32_bf16(a, b1, acc1[mt], 0, 0, 0);
            }
        }
    }

    // epilogue: fp16 partial stores (RNE via v_cvt_f16_f32)
    _Float16* myp = part + kg * SLICE;
#pragma unroll
    for (int mt = 0; mt < 4; ++mt) {
#pragma unroll
        for (int r = 0; r < 4; ++r) {
            const int m = mt * 16 + q * 4 + r;
            myp[m * OUT_F + n0] = (_Float16)acc0[mt][r];
            myp[m * OUT_F + n1] = (_Float16)acc1[mt][r];
        }
    }
}

// ---- pass 3: sum KSPLIT fp16 partial slices + bias -> fp32 out ----
__global__ __launch_bounds__(256) void reduce_kernel(
    const _Float16* __restrict__ part, const float* __restrict__ bias,
    float* __restrict__ out) {
    const int i8 = (blockIdx.x * 256 + threadIdx.x) * 8;
    const int n  = i8 % OUT_F;   // OUT_F % 8 == 0: stays within one row
    float s[8];
#pragma unroll
    for (int j = 0; j < 8; ++j) s[j] = bias[n + j];
#pragma unroll
    for (int kg = 0; kg < KSPLIT; ++kg) {
        half8 p = *(const half8*)(part + kg * SLICE + i8);
#pragma unroll
        for (int j = 0; j < 8; ++j) s[j] += (float)p[j];
    }
    *(float4v*)(out + i8)     = (float4v){s[0], s[1], s[2], s[3]};
    *(float4v*)(out + i8 + 4) = (float4v){s[4], s[5], s[6], s[7]};
}

extern "C" void kernel_launch(void* const* d_in, const int* in_sizes, int n_in,
                              void* d_out, int out_size, void* d_ws, size_t ws_size,
                              hipStream_t stream) {
    const float* x       = (const float*)d_in[0];
    const int*   qweight = (const int*)d_in[1];
    const int*   qzeros  = (const int*)d_in[2];
    const float* scales  = (const float*)d_in[3];
    // d_in[4] = g_idx (structurally k/128; unused)
    const float* bias    = (const float*)d_in[5];
    float* out = (float*)d_out;

    short*    xbf2 = (short*)d_ws;                        // 512 KB
    _Float16* part = (_Float16*)((char*)d_ws + (1 << 20)); // 22.5 MB @ +1 MB

    cvt_kernel<<<dim3((IN_F / 8) * M_ROWS / 256), dim3(256), 0, stream>>>(x, xbf2);
    qlin_kernel<<<dim3(NBLK_N * KSPLIT), dim3(256), 0, stream>>>(
        xbf2, qweight, qzeros, scales, part);
    reduce_kernel<<<dim3(SLICE / 8 / 256), dim3(256), 0, stream>>>(part, bias, out);
}